// Round 1
// baseline (2112.864 us; speedup 1.0000x reference)
//
#include <hip/hip_runtime.h>
#include <stdint.h>

// ---- problem constants ----
#define NTOK   49                // tokens per window (7x7)
#define DIMC   192
#define NHEAD  6
#define HDIM   32
#define BATCH  64
#define MROWS  (BATCH * 64 * NTOK)   // 200704 rows (= B * nW * N = B*H*W)
#define SCALE_ 0.17677669529663687f  // 32^-0.5

typedef __attribute__((ext_vector_type(8))) short bf16x8;
typedef __attribute__((ext_vector_type(4))) float f32x4;

union V8 { uint4 u; unsigned short s[8]; };

__device__ __forceinline__ float bf2f(unsigned short u) {
  union { unsigned int i; float f; } c; c.i = ((unsigned int)u) << 16; return c.f;
}
__device__ __forceinline__ unsigned short f2bf(float f) {
  union { float f; unsigned int i; } c; c.f = f;
  unsigned int lsb = (c.i >> 16) & 1;
  return (unsigned short)((c.i + 0x7fffu + lsb) >> 16);
}

// ---------------- LayerNorm (+ optional shifted window partition) ----------------
// one wave per row; 192 channels = 3 per lane
template<bool WINDOWED>
__global__ __launch_bounds__(256) void ln_k(const float* __restrict__ X,
    const float* __restrict__ g, const float* __restrict__ b,
    unsigned short* __restrict__ out, int shift)
{
  int wr = blockIdx.x * 4 + (threadIdx.x >> 6);
  int lane = threadIdx.x & 63;
  size_t srow;
  if (WINDOWED) {
    int win = wr / 49, n = wr % 49;
    int bi = win >> 6, w64 = win & 63;
    int wh = w64 >> 3, ww = w64 & 7;
    int ti = n / 7, tj = n % 7;
    int gh = wh * 7 + ti + shift; if (gh >= 56) gh -= 56;
    int gw = ww * 7 + tj + shift; if (gw >= 56) gw -= 56;
    srow = (size_t)bi * 3136 + gh * 56 + gw;
  } else {
    srow = (size_t)wr;
  }
  const float* xr = X + srow * 192;
  float v0 = xr[lane], v1 = xr[lane + 64], v2 = xr[lane + 128];
  float s  = v0 + v1 + v2;
  float s2 = v0*v0 + v1*v1 + v2*v2;
  #pragma unroll
  for (int m = 32; m >= 1; m >>= 1) { s += __shfl_xor(s, m); s2 += __shfl_xor(s2, m); }
  float mean = s * (1.0f/192.0f);
  float var  = s2 * (1.0f/192.0f) - mean*mean;
  float inv  = rsqrtf(var + 1e-5f);
  unsigned short* orow = out + (size_t)wr * 192;
  orow[lane]       = f2bf((v0-mean)*inv*g[lane]      + b[lane]);
  orow[lane+64]    = f2bf((v1-mean)*inv*g[lane+64]   + b[lane+64]);
  orow[lane+128]   = f2bf((v2-mean)*inv*g[lane+128]  + b[lane+128]);
}

// ---------------- Generic MFMA GEMM: C = A(bf16, MxK) @ W(fp32->bf16, KxN) + bias ----------------
// EPI: 0 = write bf16; 1 = proj (window-reverse scatter + residual, N==192);
//      2 = GELU, write bf16;  3 = plain residual add (N==192)
template<int EPI, int K>
__global__ __launch_bounds__(256) void gemm_k(
    const unsigned short* __restrict__ A,
    const float* __restrict__ W,
    const float* __restrict__ bias,
    unsigned short* __restrict__ Cbf,
    const float* __restrict__ Xres,
    float* __restrict__ Xdst,
    int N, int shift)
{
  __shared__ unsigned short As[128][40];   // +8 pad: ~2-way banked reads (free)
  __shared__ unsigned short Bs[64][40];    // B stored transposed: Bs[n][k]
  const int tid = threadIdx.x;
  const int lane = tid & 63, wv = tid >> 6;
  const int wm = wv >> 1, wn = wv & 1;     // 2x2 waves over 128x64 tile
  const int row0 = blockIdx.x * 128;
  const int n0   = blockIdx.y * 64;
  f32x4 acc[4][2] = {};
  const int sr  = tid >> 1, ssg = (tid & 1) * 16;   // A stage: 16 bf16 per thread
  const int bk  = tid >> 3, bsg = (tid & 7) * 8;    // B stage: 8 floats per thread
  for (int k0 = 0; k0 < K; k0 += 32) {
    const uint4* asrc = reinterpret_cast<const uint4*>(A + (size_t)(row0 + sr) * K + k0 + ssg);
    uint4 av0 = asrc[0], av1 = asrc[1];
    const float4* wsrc = reinterpret_cast<const float4*>(W + (size_t)(k0 + bk) * N + n0 + bsg);
    float4 w0 = wsrc[0], w1 = wsrc[1];
    __syncthreads();   // previous iteration's LDS reads done
    *reinterpret_cast<uint4*>(&As[sr][ssg])     = av0;
    *reinterpret_cast<uint4*>(&As[sr][ssg + 8]) = av1;
    Bs[bsg+0][bk] = f2bf(w0.x); Bs[bsg+1][bk] = f2bf(w0.y);
    Bs[bsg+2][bk] = f2bf(w0.z); Bs[bsg+3][bk] = f2bf(w0.w);
    Bs[bsg+4][bk] = f2bf(w1.x); Bs[bsg+5][bk] = f2bf(w1.y);
    Bs[bsg+6][bk] = f2bf(w1.z); Bs[bsg+7][bk] = f2bf(w1.w);
    __syncthreads();
    const int fr = lane & 15, kq = (lane >> 4) * 8;
    bf16x8 bfr[2];
    #pragma unroll
    for (int ni = 0; ni < 2; ++ni)
      bfr[ni] = *reinterpret_cast<const bf16x8*>(&Bs[wn*32 + ni*16 + fr][kq]);
    #pragma unroll
    for (int mi = 0; mi < 4; ++mi) {
      bf16x8 afr = *reinterpret_cast<const bf16x8*>(&As[wm*64 + mi*16 + fr][kq]);
      #pragma unroll
      for (int ni = 0; ni < 2; ++ni)
        acc[mi][ni] = __builtin_amdgcn_mfma_f32_16x16x32_bf16(afr, bfr[ni], acc[mi][ni], 0, 0, 0);
    }
  }
  const int lcol = lane & 15, lr4 = (lane >> 4) * 4;
  #pragma unroll
  for (int mi = 0; mi < 4; ++mi)
  #pragma unroll
  for (int ni = 0; ni < 2; ++ni)
  #pragma unroll
  for (int i = 0; i < 4; ++i) {
    int gr = row0 + wm*64 + mi*16 + lr4 + i;
    int gc = n0 + wn*32 + ni*16 + lcol;
    float v = acc[mi][ni][i] + bias[gc];
    if (EPI == 0) {
      Cbf[(size_t)gr * N + gc] = f2bf(v);
    } else if (EPI == 2) {
      float gv = 0.5f * v * (1.0f + erff(v * 0.70710678118654752f));
      Cbf[(size_t)gr * N + gc] = f2bf(gv);
    } else if (EPI == 1) {
      int win = gr / 49, n = gr % 49;
      int bi = win >> 6, w64 = win & 63;
      int wh = w64 >> 3, ww = w64 & 7;
      int ti = n / 7, tj = n % 7;
      int gh = wh*7 + ti + shift; if (gh >= 56) gh -= 56;
      int gw = ww*7 + tj + shift; if (gw >= 56) gw -= 56;
      size_t idx = ((size_t)bi * 3136 + gh * 56 + gw) * 192 + gc;
      Xdst[idx] = Xres[idx] + v;
    } else {
      size_t idx = (size_t)gr * 192 + gc;
      Xdst[idx] = Xres[idx] + v;
    }
  }
}

// ---------------- Windowed attention: one wave per (window, head) ----------------
// qkv layout: (win, tok, [q0..q191, k0..k191, v0..v191]) bf16
template<bool SHIFTED>
__global__ __launch_bounds__(64) void attn_k(
    const unsigned short* __restrict__ qkv,
    const float* __restrict__ rpb,      // (169, 6) fp32, depth-offset applied
    unsigned short* __restrict__ out)   // (win, tok, 192) bf16
{
  __shared__ float kv[2][49][32];
  int blk = blockIdx.x;
  int win = blk / 6, h = blk - win * 6;
  int lane = threadIdx.x;
  const unsigned short* base = qkv + (size_t)win * 49 * 576;
  for (int idx = lane; idx < 196; idx += 64) {          // 49 rows x 4 segs of 8
    int n = idx >> 2, sg = (idx & 3) * 8;
    V8 kk, vv;
    kk.u = *reinterpret_cast<const uint4*>(base + n*576 + 192 + h*32 + sg);
    vv.u = *reinterpret_cast<const uint4*>(base + n*576 + 384 + h*32 + sg);
    #pragma unroll
    for (int j = 0; j < 8; ++j) { kv[0][n][sg+j] = bf2f(kk.s[j]); kv[1][n][sg+j] = bf2f(vv.s[j]); }
  }
  __syncthreads();
  if (lane < 49) {
    float q[32];
    const unsigned short* qr = base + (size_t)lane * 576 + h * 32;
    #pragma unroll
    for (int sg = 0; sg < 4; ++sg) {
      V8 qq; qq.u = *reinterpret_cast<const uint4*>(qr + sg*8);
      #pragma unroll
      for (int j = 0; j < 8; ++j) q[sg*8+j] = bf2f(qq.s[j]) * SCALE_;
    }
    int ti = lane / 7, tj = lane - ti * 7;
    int wi = win & 63, wh = wi >> 3, ww = wi & 7;
    int rid = 0;
    if (SHIFTED) {
      int hh = wh*7 + ti, wg = ww*7 + tj;
      rid = (hh < 49 ? 0 : (hh < 53 ? 1 : 2)) * 3 + (wg < 49 ? 0 : (wg < 53 ? 1 : 2));
    }
    float s[49];
    float mx = -1e30f;
    #pragma unroll
    for (int m = 0; m < 49; ++m) {
      float a = 0.f;
      #pragma unroll
      for (int d4 = 0; d4 < 8; ++d4) {
        float4 kf = *reinterpret_cast<const float4*>(&kv[0][m][d4*4]);
        a += q[d4*4+0]*kf.x + q[d4*4+1]*kf.y + q[d4*4+2]*kf.z + q[d4*4+3]*kf.w;
      }
      int mi = m / 7, mj = m - mi * 7;
      a += rpb[((ti - mi + 6) * 13 + (tj - mj + 6)) * 6 + h];
      if (SHIFTED) {
        int hh = wh*7 + mi, wg = ww*7 + mj;
        int rid2 = (hh < 49 ? 0 : (hh < 53 ? 1 : 2)) * 3 + (wg < 49 ? 0 : (wg < 53 ? 1 : 2));
        if (rid2 != rid) a -= 100.f;
      }
      s[m] = a;
      mx = fmaxf(mx, a);
    }
    float sum = 0.f;
    #pragma unroll
    for (int m = 0; m < 49; ++m) { float e = __expf(s[m] - mx); s[m] = e; sum += e; }
    float rs = 1.f / sum;
    float o[32];
    #pragma unroll
    for (int d = 0; d < 32; ++d) o[d] = 0.f;
    #pragma unroll
    for (int m = 0; m < 49; ++m) {
      float p = s[m] * rs;
      #pragma unroll
      for (int d4 = 0; d4 < 8; ++d4) {
        float4 vf = *reinterpret_cast<const float4*>(&kv[1][m][d4*4]);
        o[d4*4+0] += p*vf.x; o[d4*4+1] += p*vf.y; o[d4*4+2] += p*vf.z; o[d4*4+3] += p*vf.w;
      }
    }
    unsigned short* orow = out + ((size_t)win * 49 + lane) * 192 + h * 32;
    #pragma unroll
    for (int sg = 0; sg < 4; ++sg) {
      V8 pk;
      #pragma unroll
      for (int j = 0; j < 8; ++j) pk.s[j] = f2bf(o[sg*8+j]);
      *reinterpret_cast<uint4*>(orow + sg*8) = pk.u;
    }
  }
}

// ---------------- launch ----------------
extern "C" void kernel_launch(void* const* d_in, const int* in_sizes, int n_in,
                              void* d_out, int out_size, void* d_ws, size_t ws_size,
                              hipStream_t stream) {
  const float* x    = (const float*)d_in[0];
  const float* n1g  = (const float*)d_in[1];
  const float* n1b  = (const float*)d_in[2];
  const float* qkvw = (const float*)d_in[3];
  const float* qkvb = (const float*)d_in[4];
  const float* rpb  = (const float*)d_in[5];
  const float* pw   = (const float*)d_in[6];
  const float* pb   = (const float*)d_in[7];
  const float* n2g  = (const float*)d_in[8];
  const float* n2b  = (const float*)d_in[9];
  const float* f1w  = (const float*)d_in[10];
  const float* f1b  = (const float*)d_in[11];
  const float* f2w  = (const float*)d_in[12];
  const float* f2b  = (const float*)d_in[13];
  float* out = (float*)d_out;

  // workspace layout: x1 (fp32, 154.1MB) | Abuf (bf16 192-col, 77.1MB) | Bbuf (bf16 768-col, 308.3MB)
  const size_t XBYTES = (size_t)MROWS * 192 * 4;
  const size_t ABYTES = (size_t)MROWS * 192 * 2;
  char* ws = (char*)d_ws;
  float* x1 = (float*)ws;
  unsigned short* Abuf = (unsigned short*)(ws + XBYTES);
  unsigned short* Bbuf = (unsigned short*)(ws + XBYTES + ABYTES);

  const int LNBLK = MROWS / 4;       // 50176
  const dim3 G_QKV(MROWS/128, 9), G_P(MROWS/128, 3), G_F1(MROWS/128, 12), G_F2(MROWS/128, 3);

  for (int i = 0; i < 2; ++i) {
    int shift = i ? 3 : 0;
    const float* xin = i ? (const float*)x1 : x;
    float* xfin = i ? out : x1;
    // 1. LN1 + shifted window partition -> Abuf (windowed rows, bf16)
    ln_k<true><<<LNBLK, 256, 0, stream>>>(xin, n1g + i*192, n1b + i*192, Abuf, shift);
    // 2. QKV gemm -> Bbuf (M x 576 bf16)
    gemm_k<0,192><<<G_QKV, 256, 0, stream>>>(Abuf, qkvw + (size_t)i*192*576, qkvb + i*576,
                                             Bbuf, nullptr, nullptr, 576, 0);
    // 3. attention -> Abuf (windowed rows, 192 bf16)
    if (shift) attn_k<true ><<<BATCH*64*NHEAD, 64, 0, stream>>>(Bbuf, rpb + i*169*6, Abuf);
    else       attn_k<false><<<BATCH*64*NHEAD, 64, 0, stream>>>(Bbuf, rpb + i*169*6, Abuf);
    // 4. proj gemm + window-reverse scatter residual -> x1 (fp32)
    gemm_k<1,192><<<G_P, 256, 0, stream>>>(Abuf, pw + (size_t)i*192*192, pb + i*192,
                                           nullptr, xin, x1, 192, shift);
    // 5. LN2 -> Abuf (natural rows, bf16)
    ln_k<false><<<LNBLK, 256, 0, stream>>>(x1, n2g + i*192, n2b + i*192, Abuf, 0);
    // 6. FC1 + GELU -> Bbuf (M x 768 bf16)
    gemm_k<2,192><<<G_F1, 256, 0, stream>>>(Abuf, f1w + (size_t)i*192*768, f1b + i*768,
                                            Bbuf, nullptr, nullptr, 768, 0);
    // 7. FC2 + residual -> x1 (depth 0) / d_out (depth 1)
    gemm_k<3,768><<<G_F2, 256, 0, stream>>>(Bbuf, f2w + (size_t)i*768*192, f2b + i*192,
                                            nullptr, x1, xfin, 192, 0);
  }
}

// Round 2
// 1881.970 us; speedup vs baseline: 1.1227x; 1.1227x over previous
//
#include <hip/hip_runtime.h>
#include <stdint.h>

// ---- problem constants ----
#define NTOK   49
#define BATCH  64
#define MROWS  (BATCH * 64 * NTOK)   // 200704 rows
#define SCALE_ 0.17677669529663687f  // 32^-0.5

typedef __attribute__((ext_vector_type(8))) short bf16x8;
typedef __attribute__((ext_vector_type(4))) float f32x4;

union V8 { uint4 u; unsigned short s[8]; };

__device__ __forceinline__ float bf2f(unsigned short u) {
  union { unsigned int i; float f; } c; c.i = ((unsigned int)u) << 16; return c.f;
}
__device__ __forceinline__ unsigned short f2bf(float f) {
  union { float f; unsigned int i; } c; c.f = f;
  unsigned int lsb = (c.i >> 16) & 1;
  return (unsigned short)((c.i + 0x7fffu + lsb) >> 16);
}

// ---------------- weight convert+transpose: W (K x N fp32) -> Wt (N x K bf16) ----------------
__global__ __launch_bounds__(256) void wt_k(const float* __restrict__ W,
    unsigned short* __restrict__ Wt, int K, int N)
{
  int idx = blockIdx.x * 256 + threadIdx.x;
  if (idx < K * N) {
    int k = idx / N, n = idx - k * N;
    Wt[(size_t)n * K + k] = f2bf(W[idx]);
  }
}

// ---------------- LayerNorm + shifted window partition ----------------
__global__ __launch_bounds__(256) void ln_k(const float* __restrict__ X,
    const float* __restrict__ g, const float* __restrict__ b,
    unsigned short* __restrict__ out, int shift)
{
  int wr = blockIdx.x * 4 + (threadIdx.x >> 6);
  int lane = threadIdx.x & 63;
  int win = wr / 49, n = wr % 49;
  int bi = win >> 6, w64 = win & 63;
  int wh = w64 >> 3, ww = w64 & 7;
  int ti = n / 7, tj = n % 7;
  int gh = wh * 7 + ti + shift; if (gh >= 56) gh -= 56;
  int gw = ww * 7 + tj + shift; if (gw >= 56) gw -= 56;
  size_t srow = (size_t)bi * 3136 + gh * 56 + gw;
  const float* xr = X + srow * 192;
  float v0 = xr[lane], v1 = xr[lane + 64], v2 = xr[lane + 128];
  float s  = v0 + v1 + v2;
  float s2 = v0*v0 + v1*v1 + v2*v2;
  #pragma unroll
  for (int m = 32; m >= 1; m >>= 1) { s += __shfl_xor(s, m); s2 += __shfl_xor(s2, m); }
  float mean = s * (1.0f/192.0f);
  float var  = s2 * (1.0f/192.0f) - mean*mean;
  float inv  = rsqrtf(var + 1e-5f);
  unsigned short* orow = out + (size_t)wr * 192;
  orow[lane]       = f2bf((v0-mean)*inv*g[lane]      + b[lane]);
  orow[lane+64]    = f2bf((v1-mean)*inv*g[lane+64]   + b[lane+64]);
  orow[lane+128]   = f2bf((v2-mean)*inv*g[lane+128]  + b[lane+128]);
}

// ---------------- MFMA GEMM (K=192): A (bf16 LDS-staged) x Wt (bf16, direct global) ----------------
// EPI: 0 = write bf16 (qkv); 1 = proj: window-reverse scatter + residual (N==192)
template<int EPI>
__global__ __launch_bounds__(256) void gemm2_k(
    const unsigned short* __restrict__ A,
    const unsigned short* __restrict__ Wt,   // [N][192] bf16
    const float* __restrict__ bias,
    unsigned short* __restrict__ Cbf,
    const float* __restrict__ Xres,
    float* __restrict__ Xdst,
    int N, int shift)
{
  __shared__ unsigned short As[128][40];   // pad 40: 2-way banked reads (free)
  const int tid = threadIdx.x;
  const int lane = tid & 63, wv = tid >> 6;
  const int wm = wv >> 1, wn = wv & 1;     // 2x2 waves over 128x64 tile
  const int row0 = blockIdx.x * 128;
  const int n0   = blockIdx.y * 64;
  f32x4 acc[4][2] = {};
  const int sr  = tid >> 1, ssg = (tid & 1) * 16;
  const int fr = lane & 15, kq = (lane >> 4) * 8;
  #pragma unroll
  for (int k0 = 0; k0 < 192; k0 += 32) {
    const uint4* asrc = reinterpret_cast<const uint4*>(A + (size_t)(row0 + sr) * 192 + k0 + ssg);
    uint4 av0 = asrc[0], av1 = asrc[1];
    __syncthreads();   // previous iteration's LDS reads done
    *reinterpret_cast<uint4*>(&As[sr][ssg])     = av0;
    *reinterpret_cast<uint4*>(&As[sr][ssg + 8]) = av1;
    __syncthreads();
    bf16x8 bfr[2];
    #pragma unroll
    for (int ni = 0; ni < 2; ++ni)
      bfr[ni] = *reinterpret_cast<const bf16x8*>(&Wt[(size_t)(n0 + wn*32 + ni*16 + fr) * 192 + k0 + kq]);
    #pragma unroll
    for (int mi = 0; mi < 4; ++mi) {
      bf16x8 afr = *reinterpret_cast<const bf16x8*>(&As[wm*64 + mi*16 + fr][kq]);
      #pragma unroll
      for (int ni = 0; ni < 2; ++ni)
        acc[mi][ni] = __builtin_amdgcn_mfma_f32_16x16x32_bf16(afr, bfr[ni], acc[mi][ni], 0, 0, 0);
    }
  }
  const int lcol = lane & 15, lr4 = (lane >> 4) * 4;
  #pragma unroll
  for (int mi = 0; mi < 4; ++mi)
  #pragma unroll
  for (int ni = 0; ni < 2; ++ni)
  #pragma unroll
  for (int i = 0; i < 4; ++i) {
    int gr = row0 + wm*64 + mi*16 + lr4 + i;
    int gc = n0 + wn*32 + ni*16 + lcol;
    float v = acc[mi][ni][i] + bias[gc];
    if (EPI == 0) {
      Cbf[(size_t)gr * N + gc] = f2bf(v);
    } else {
      int win = gr / 49, n = gr % 49;
      int bi = win >> 6, w64 = win & 63;
      int wh = w64 >> 3, ww = w64 & 7;
      int ti = n / 7, tj = n % 7;
      int gh = wh*7 + ti + shift; if (gh >= 56) gh -= 56;
      int gw = ww*7 + tj + shift; if (gw >= 56) gw -= 56;
      size_t idx = ((size_t)bi * 3136 + gh * 56 + gw) * 192 + gc;
      Xdst[idx] = Xres[idx] + v;
    }
  }
}

// ---------------- Fused LN2 + FC1 + GELU + FC2 + residual ----------------
// 64 rows per block, 512 threads (8 waves). FC1 (64x768) done in two 384-col halves
// staged in LDS; FC2 accumulates across halves.
__global__ __launch_bounds__(512, 4) void mlp_k(
    const float* __restrict__ X,            // LN input AND residual (fp32 rows)
    const float* __restrict__ g, const float* __restrict__ b,
    const unsigned short* __restrict__ W1t, // [768][192] bf16
    const float* __restrict__ b1,
    const unsigned short* __restrict__ W2t, // [192][768] bf16
    const float* __restrict__ b2,
    float* __restrict__ Y)
{
  __shared__ unsigned short As[64][200];    // LN'd activations
  __shared__ unsigned short Hs[64][396];    // FC1 half (384 cols + pad)
  const int row0 = blockIdx.x * 64;
  const int tid = threadIdx.x, lane = tid & 63, wv = tid >> 6;
  // ---- LN2: wave wv handles rows wv*8 .. wv*8+7
  #pragma unroll
  for (int r = 0; r < 8; ++r) {
    int row = wv * 8 + r;
    const float* xr = X + (size_t)(row0 + row) * 192;
    float v0 = xr[lane], v1 = xr[lane + 64], v2 = xr[lane + 128];
    float s  = v0 + v1 + v2;
    float s2 = v0*v0 + v1*v1 + v2*v2;
    #pragma unroll
    for (int m = 32; m >= 1; m >>= 1) { s += __shfl_xor(s, m); s2 += __shfl_xor(s2, m); }
    float mean = s * (1.0f/192.0f);
    float var  = s2 * (1.0f/192.0f) - mean*mean;
    float inv  = rsqrtf(var + 1e-5f);
    As[row][lane]       = f2bf((v0-mean)*inv*g[lane]      + b[lane]);
    As[row][lane+64]    = f2bf((v1-mean)*inv*g[lane+64]   + b[lane+64]);
    As[row][lane+128]   = f2bf((v2-mean)*inv*g[lane+128]  + b[lane+128]);
  }
  __syncthreads();
  const int fr = lane & 15, kq = (lane >> 4) * 8;
  const int lcol = lane & 15, lr4 = (lane >> 4) * 4;
  const int wm2 = wv >> 2, wn2 = wv & 3;    // FC2 wave grid: 2 x 4
  f32x4 acc2[2][3] = {};
  for (int hh = 0; hh < 2; ++hh) {
    // ---- FC1: this wave computes 64 rows x 48 cols at cols hh*384 + wv*48
    f32x4 acc1[4][3] = {};
    const int c0 = hh * 384 + wv * 48;
    #pragma unroll
    for (int k0 = 0; k0 < 192; k0 += 32) {
      bf16x8 bfr[3];
      #pragma unroll
      for (int ni = 0; ni < 3; ++ni)
        bfr[ni] = *reinterpret_cast<const bf16x8*>(&W1t[(size_t)(c0 + ni*16 + fr) * 192 + k0 + kq]);
      #pragma unroll
      for (int mi = 0; mi < 4; ++mi) {
        bf16x8 afr = *reinterpret_cast<const bf16x8*>(&As[mi*16 + fr][k0 + kq]);
        #pragma unroll
        for (int ni = 0; ni < 3; ++ni)
          acc1[mi][ni] = __builtin_amdgcn_mfma_f32_16x16x32_bf16(afr, bfr[ni], acc1[mi][ni], 0, 0, 0);
      }
    }
    // GELU -> Hs (local cols 0..383)
    #pragma unroll
    for (int mi = 0; mi < 4; ++mi)
    #pragma unroll
    for (int ni = 0; ni < 3; ++ni)
    #pragma unroll
    for (int i = 0; i < 4; ++i) {
      int rr = mi*16 + lr4 + i;
      int cc = wv*48 + ni*16 + lcol;
      float v = acc1[mi][ni][i] + b1[hh*384 + cc];
      float gv = 0.5f * v * (1.0f + erff(v * 0.70710678118654752f));
      Hs[rr][cc] = f2bf(gv);
    }
    __syncthreads();
    // ---- FC2 partial over this half's 384 k's
    #pragma unroll
    for (int k0 = 0; k0 < 384; k0 += 32) {
      bf16x8 bfr[3];
      #pragma unroll
      for (int ni = 0; ni < 3; ++ni)
        bfr[ni] = *reinterpret_cast<const bf16x8*>(&W2t[(size_t)(wn2*48 + ni*16 + fr) * 768 + hh*384 + k0 + kq]);
      #pragma unroll
      for (int mi = 0; mi < 2; ++mi) {
        bf16x8 afr = *reinterpret_cast<const bf16x8*>(&Hs[wm2*32 + mi*16 + fr][k0 + kq]);
        #pragma unroll
        for (int ni = 0; ni < 3; ++ni)
          acc2[mi][ni] = __builtin_amdgcn_mfma_f32_16x16x32_bf16(afr, bfr[ni], acc2[mi][ni], 0, 0, 0);
      }
    }
    __syncthreads();   // Hs free for next half
  }
  // ---- FC2 epilogue: + bias + residual (fp32 out)
  #pragma unroll
  for (int mi = 0; mi < 2; ++mi)
  #pragma unroll
  for (int ni = 0; ni < 3; ++ni)
  #pragma unroll
  for (int i = 0; i < 4; ++i) {
    int grow = row0 + wm2*32 + mi*16 + lr4 + i;
    int gc = wn2*48 + ni*16 + lcol;
    float v = acc2[mi][ni][i] + b2[gc];
    size_t idx = (size_t)grow * 192 + gc;
    Y[idx] = X[idx] + v;
  }
}

// ---------------- Windowed attention: one wave per (window, head) ----------------
template<bool SHIFTED>
__global__ __launch_bounds__(64) void attn_k(
    const unsigned short* __restrict__ qkv,
    const float* __restrict__ rpb,
    unsigned short* __restrict__ out)
{
  __shared__ float kv[2][49][32];
  int blk = blockIdx.x;
  int win = blk / 6, h = blk - win * 6;
  int lane = threadIdx.x;
  const unsigned short* base = qkv + (size_t)win * 49 * 576;
  for (int idx = lane; idx < 196; idx += 64) {
    int n = idx >> 2, sg = (idx & 3) * 8;
    V8 kk, vv;
    kk.u = *reinterpret_cast<const uint4*>(base + n*576 + 192 + h*32 + sg);
    vv.u = *reinterpret_cast<const uint4*>(base + n*576 + 384 + h*32 + sg);
    #pragma unroll
    for (int j = 0; j < 8; ++j) { kv[0][n][sg+j] = bf2f(kk.s[j]); kv[1][n][sg+j] = bf2f(vv.s[j]); }
  }
  __syncthreads();
  if (lane < 49) {
    float q[32];
    const unsigned short* qr = base + (size_t)lane * 576 + h * 32;
    #pragma unroll
    for (int sg = 0; sg < 4; ++sg) {
      V8 qq; qq.u = *reinterpret_cast<const uint4*>(qr + sg*8);
      #pragma unroll
      for (int j = 0; j < 8; ++j) q[sg*8+j] = bf2f(qq.s[j]) * SCALE_;
    }
    int ti = lane / 7, tj = lane - ti * 7;
    int wi = win & 63, wh = wi >> 3, ww = wi & 7;
    int rid = 0;
    if (SHIFTED) {
      int hh = wh*7 + ti, wg = ww*7 + tj;
      rid = (hh < 49 ? 0 : (hh < 53 ? 1 : 2)) * 3 + (wg < 49 ? 0 : (wg < 53 ? 1 : 2));
    }
    float s[49];
    float mx = -1e30f;
    #pragma unroll
    for (int m = 0; m < 49; ++m) {
      float a = 0.f;
      #pragma unroll
      for (int d4 = 0; d4 < 8; ++d4) {
        float4 kf = *reinterpret_cast<const float4*>(&kv[0][m][d4*4]);
        a += q[d4*4+0]*kf.x + q[d4*4+1]*kf.y + q[d4*4+2]*kf.z + q[d4*4+3]*kf.w;
      }
      int mi = m / 7, mj = m - mi * 7;
      a += rpb[((ti - mi + 6) * 13 + (tj - mj + 6)) * 6 + h];
      if (SHIFTED) {
        int hh = wh*7 + mi, wg = ww*7 + mj;
        int rid2 = (hh < 49 ? 0 : (hh < 53 ? 1 : 2)) * 3 + (wg < 49 ? 0 : (wg < 53 ? 1 : 2));
        if (rid2 != rid) a -= 100.f;
      }
      s[m] = a;
      mx = fmaxf(mx, a);
    }
    float sum = 0.f;
    #pragma unroll
    for (int m = 0; m < 49; ++m) { float e = __expf(s[m] - mx); s[m] = e; sum += e; }
    float rs = 1.f / sum;
    float o[32];
    #pragma unroll
    for (int d = 0; d < 32; ++d) o[d] = 0.f;
    #pragma unroll
    for (int m = 0; m < 49; ++m) {
      float p = s[m] * rs;
      #pragma unroll
      for (int d4 = 0; d4 < 8; ++d4) {
        float4 vf = *reinterpret_cast<const float4*>(&kv[1][m][d4*4]);
        o[d4*4+0] += p*vf.x; o[d4*4+1] += p*vf.y; o[d4*4+2] += p*vf.z; o[d4*4+3] += p*vf.w;
      }
    }
    unsigned short* orow = out + ((size_t)win * 49 + lane) * 192 + h * 32;
    #pragma unroll
    for (int sg = 0; sg < 4; ++sg) {
      V8 pk;
      #pragma unroll
      for (int j = 0; j < 8; ++j) pk.s[j] = f2bf(o[sg*8+j]);
      *reinterpret_cast<uint4*>(orow + sg*8) = pk.u;
    }
  }
}

// ---------------- launch ----------------
extern "C" void kernel_launch(void* const* d_in, const int* in_sizes, int n_in,
                              void* d_out, int out_size, void* d_ws, size_t ws_size,
                              hipStream_t stream) {
  const float* x    = (const float*)d_in[0];
  const float* n1g  = (const float*)d_in[1];
  const float* n1b  = (const float*)d_in[2];
  const float* qkvw = (const float*)d_in[3];
  const float* qkvb = (const float*)d_in[4];
  const float* rpb  = (const float*)d_in[5];
  const float* pw   = (const float*)d_in[6];
  const float* pb   = (const float*)d_in[7];
  const float* n2g  = (const float*)d_in[8];
  const float* n2b  = (const float*)d_in[9];
  const float* f1w  = (const float*)d_in[10];
  const float* f1b  = (const float*)d_in[11];
  const float* f2w  = (const float*)d_in[12];
  const float* f2b  = (const float*)d_in[13];
  float* out = (float*)d_out;

  // workspace: x1 fp32 | Abuf bf16 (192 col) | Bbuf bf16 (576 col) | Wt arena
  const size_t XBYTES = (size_t)MROWS * 192 * 4;     // 154.1 MB
  const size_t ABYTES = (size_t)MROWS * 192 * 2;     // 77.1 MB
  const size_t QBYTES = (size_t)MROWS * 576 * 2;     // 231.2 MB
  char* ws = (char*)d_ws;
  float* x1 = (float*)ws;
  unsigned short* Abuf = (unsigned short*)(ws + XBYTES);
  unsigned short* Bbuf = (unsigned short*)(ws + XBYTES + ABYTES);
  unsigned short* WT   = (unsigned short*)(ws + XBYTES + ABYTES + QBYTES);
  // per-depth bf16 transposed weights
  const size_t WQ = 110592, WP = 36864, W1 = 147456, W2 = 147456;
  const size_t WD = WQ + WP + W1 + W2;   // 442368

  // convert weights (tiny; runs per call, deterministic)
  for (int d = 0; d < 2; ++d) {
    unsigned short* wt = WT + d * WD;
    wt_k<<<(int)((WQ + 255)/256), 256, 0, stream>>>(qkvw + (size_t)d*WQ, wt,                 192, 576);
    wt_k<<<(int)((WP + 255)/256), 256, 0, stream>>>(pw   + (size_t)d*WP, wt + WQ,            192, 192);
    wt_k<<<(int)((W1 + 255)/256), 256, 0, stream>>>(f1w  + (size_t)d*W1, wt + WQ + WP,       192, 768);
    wt_k<<<(int)((W2 + 255)/256), 256, 0, stream>>>(f2w  + (size_t)d*W2, wt + WQ + WP + W1,  768, 192);
  }

  const int LNBLK = MROWS / 4;
  const dim3 G_QKV(MROWS/128, 9), G_P(MROWS/128, 3);

  for (int i = 0; i < 2; ++i) {
    int shift = i ? 3 : 0;
    const float* xin = i ? (const float*)x1 : x;
    float* xfin = i ? out : x1;
    const unsigned short* wt = WT + i * WD;
    // 1. LN1 + shifted window partition -> Abuf
    ln_k<<<LNBLK, 256, 0, stream>>>(xin, n1g + i*192, n1b + i*192, Abuf, shift);
    // 2. QKV gemm -> Bbuf
    gemm2_k<0><<<G_QKV, 256, 0, stream>>>(Abuf, wt, qkvb + i*576, Bbuf, nullptr, nullptr, 576, 0);
    // 3. attention -> Abuf
    if (shift) attn_k<true ><<<BATCH*64*6, 64, 0, stream>>>(Bbuf, rpb + i*169*6, Abuf);
    else       attn_k<false><<<BATCH*64*6, 64, 0, stream>>>(Bbuf, rpb + i*169*6, Abuf);
    // 4. proj gemm + window-reverse scatter residual -> x1
    gemm2_k<1><<<G_P, 256, 0, stream>>>(Abuf, wt + WQ, pb + i*192, nullptr, xin, x1, 192, shift);
    // 5-7. fused LN2 + FC1 + GELU + FC2 + residual
    mlp_k<<<MROWS/64, 512, 0, stream>>>(x1, n2g + i*192, n2b + i*192,
                                        wt + WQ + WP, f1b + i*768,
                                        wt + WQ + WP + W1, f2b + i*192, xfin);
  }
}